// Round 1
// baseline (212.651 us; speedup 1.0000x reference)
//
#include <hip/hip_runtime.h>

typedef unsigned short u16;
typedef unsigned int   u32;
typedef __bf16  bf16x8 __attribute__((ext_vector_type(8)));
typedef float   f32x4  __attribute__((ext_vector_type(4)));

#define NN  4096
#define CCH 64
#define CQ  32

__device__ __forceinline__ u32 rbf(float a) {
  u32 u = __builtin_bit_cast(u32, a);
  return (u + 0x7fffu + ((u >> 16) & 1u)) >> 16;   // RNE f32 -> bf16 bits
}
__device__ __forceinline__ u32 pack2bf(float a, float b) {
  return rbf(a) | (rbf(b) << 16);
}

struct __align__(8) U2 { u32 x, y; };

// -------- kernel 1: 1x1 convs -> qT[b][n][32], kT[b][n][32], v[b][c][n] (bf16)
__global__ __launch_bounds__(256) void qkv_kernel(
    const float* __restrict__ x,
    const float* __restrict__ wq, const float* __restrict__ bq,
    const float* __restrict__ wk, const float* __restrict__ bk,
    const float* __restrict__ wv, const float* __restrict__ bv,
    u16* __restrict__ qT, u16* __restrict__ kT, u16* __restrict__ vB)
{
  __shared__ float xs[64][64];
  const int b     = blockIdx.x >> 6;
  const int nbase = (blockIdx.x & 63) * 64;
  const int t   = threadIdx.x;
  const int nl  = t & 63;
  const int grp = t >> 6;

  const float* xb = x + ((size_t)b * CCH) * NN + nbase;
  #pragma unroll
  for (int k2 = 0; k2 < 16; ++k2) {
    int c = grp * 16 + k2;
    xs[c][nl] = xb[(size_t)c * NN + nl];
  }
  __syncthreads();

  float xcol[64];
  #pragma unroll
  for (int c = 0; c < 64; ++c) xcol[c] = xs[c][nl];

  const float* w; const float* bias;
  if (grp == 0)      { w = wq; bias = bq; }
  else if (grp == 1) { w = wk; bias = bk; }
  else               { w = wv + (grp - 2) * 32 * 64; bias = bv + (grp - 2) * 32; }

  const int n = nbase + nl;
  for (int i = 0; i < 32; ++i) {
    float a = bias[i];
    #pragma unroll
    for (int c = 0; c < 64; ++c) a = fmaf(w[i * 64 + c], xcol[c], a);
    u16 h = (u16)rbf(a);
    if (grp == 0)      qT[((size_t)b * NN + n) * CQ + i] = h;
    else if (grp == 1) kT[((size_t)b * NN + n) * CQ + i] = h;
    else               vB[((size_t)b * CCH + (grp - 2) * 32 + i) * NN + n] = h;
  }
}

// -------- kernel 2: flash attention (bf16 MFMA) + fused final conv + residual
__global__ __launch_bounds__(256) void attn_kernel(
    const u16* __restrict__ qT, const u16* __restrict__ kT, const u16* __restrict__ vB,
    const float* __restrict__ x, const float* __restrict__ wf, const float* __restrict__ bf,
    const float* __restrict__ gamma, float* __restrict__ out)
{
  __shared__ __align__(16) u16 plds[4][16][72];  // per-wave P scratch, 144B rows
  __shared__ float ols[64][64];                  // O tile for fused conv
  const int b  = blockIdx.x & 7;                 // batch -> XCD locality
  const int qt = blockIdx.x >> 3;
  const int t    = threadIdx.x;
  const int lane = t & 63;
  const int wid  = t >> 6;
  const int g    = lane >> 4;
  const int r16  = lane & 15;
  const int qbase = qt * 64 + wid * 16;

  const u16* qtb = qT + ((size_t)b * NN) * CQ;
  const u16* ktb = kT + ((size_t)b * NN) * CQ;
  const u16* vb  = vB + (size_t)b * CCH * NN;

  // Q fragment (B operand): col n = lane&15, k c = (lane>>4)*8 + j  -> 16B load
  const bf16x8 qf = *(const bf16x8*)(qtb + (size_t)(qbase + r16) * CQ + g * 8);

  f32x4 acc[4];
  #pragma unroll
  for (int ct = 0; ct < 4; ++ct) acc[ct] = (f32x4){0.f, 0.f, 0.f, 0.f};
  float mrun = -1e30f, lrun = 0.f;
  const float k1 = 0.0225421092623961f;  // log2(e) / sqrt(4096)

  u16* pw = &plds[wid][r16][0];

  for (int mc = 0; mc < NN; mc += 64) {
    // ---- S = K_tile . Q  (St[m][n], col = query n = r16)
    f32x4 st[4];
    #pragma unroll
    for (int s = 0; s < 4; ++s) {
      const bf16x8 kf = *(const bf16x8*)(ktb + (size_t)(mc + s * 16 + r16) * CQ + g * 8);
      st[s] = __builtin_amdgcn_mfma_f32_16x16x32_bf16(kf, qf, (f32x4){0.f,0.f,0.f,0.f}, 0, 0, 0);
    }
    // ---- online softmax (per-column state; uniform per lane)
    float tv[16];
    float tmax = -1e30f;
    #pragma unroll
    for (int s = 0; s < 4; ++s) {
      #pragma unroll
      for (int rr = 0; rr < 4; ++rr) {
        float v = st[s][rr] * k1;
        tv[s * 4 + rr] = v;
        tmax = fmaxf(tmax, v);
      }
    }
    tmax = fmaxf(tmax, __shfl_xor(tmax, 16, 64));
    tmax = fmaxf(tmax, __shfl_xor(tmax, 32, 64));
    const float mnew  = fmaxf(mrun, tmax);
    const float alpha = exp2f(mrun - mnew);
    mrun = mnew;
    lrun *= alpha;
    #pragma unroll
    for (int ct = 0; ct < 4; ++ct) {
      #pragma unroll
      for (int rr = 0; rr < 4; ++rr) acc[ct][rr] *= alpha;
    }

    float psum = 0.f;
    u32 pk[8];
    #pragma unroll
    for (int s = 0; s < 4; ++s) {
      #pragma unroll
      for (int hh = 0; hh < 2; ++hh) {
        float p0 = exp2f(tv[s * 4 + hh * 2]     - mnew);
        float p1 = exp2f(tv[s * 4 + hh * 2 + 1] - mnew);
        psum += p0 + p1;
        pk[s * 2 + hh] = pack2bf(p0, p1);
      }
    }
    lrun += psum;

    // ---- P relayout through per-wave LDS: [n][m], m contiguous
    #pragma unroll
    for (int s = 0; s < 4; ++s) {
      U2 val; val.x = pk[2 * s]; val.y = pk[2 * s + 1];
      *(U2*)((char*)pw + s * 32 + g * 8) = val;   // m = s*16 + 4g + {0..3}
    }
    // same-wave DS ops are in-order: no barrier needed

    // ---- O += V . P^T   (K=32 per MFMA, two halves of the 64-chunk)
    #pragma unroll
    for (int hh = 0; hh < 2; ++hh) {
      const bf16x8 pf = *(const bf16x8*)((const char*)pw + hh * 64 + g * 16);
      #pragma unroll
      for (int ct = 0; ct < 4; ++ct) {
        const bf16x8 vf = *(const bf16x8*)(vb + (size_t)(ct * 16 + r16) * NN + mc + hh * 32 + g * 8);
        acc[ct] = __builtin_amdgcn_mfma_f32_16x16x32_bf16(vf, pf, acc[ct], 0, 0, 0);
      }
    }
  }

  float ltot = lrun + __shfl_xor(lrun, 16, 64);
  ltot += __shfl_xor(ltot, 32, 64);
  const float oinv = 1.f / ltot;

  #pragma unroll
  for (int ct = 0; ct < 4; ++ct) {
    #pragma unroll
    for (int rr = 0; rr < 4; ++rr)
      ols[ct * 16 + g * 4 + rr][wid * 16 + r16] = acc[ct][rr] * oinv;
  }
  __syncthreads();

  // ---- fused final 1x1 conv + gamma * out + x
  const int nl = t & 63;
  const int og = t >> 6;
  float oc[64];
  #pragma unroll
  for (int c = 0; c < 64; ++c) oc[c] = ols[c][nl];
  const float gm = gamma[0];
  const size_t nidx = (size_t)qt * 64 + nl;
  for (int i = 0; i < 16; ++i) {
    const int o = og * 16 + i;
    float a = bf[o];
    #pragma unroll
    for (int c = 0; c < 64; ++c) a = fmaf(wf[o * 64 + c], oc[c], a);
    const size_t idx = ((size_t)b * CCH + o) * NN + nidx;
    out[idx] = gm * a + x[idx];
  }
}

extern "C" void kernel_launch(void* const* d_in, const int* in_sizes, int n_in,
                              void* d_out, int out_size, void* d_ws, size_t ws_size,
                              hipStream_t stream) {
  const float* x     = (const float*)d_in[0];
  const float* wq    = (const float*)d_in[1];
  const float* bq    = (const float*)d_in[2];
  const float* wk    = (const float*)d_in[3];
  const float* bk    = (const float*)d_in[4];
  const float* wv    = (const float*)d_in[5];
  const float* bv    = (const float*)d_in[6];
  const float* wf    = (const float*)d_in[7];
  const float* bf_   = (const float*)d_in[8];
  const float* gamma = (const float*)d_in[9];
  float* out = (float*)d_out;

  u16* qT = (u16*)d_ws;                 // 8*4096*32 bf16 = 2 MB
  u16* kT = qT + (size_t)8 * NN * CQ;   // 2 MB
  u16* vB = kT + (size_t)8 * NN * CQ;   // 8*64*4096 bf16 = 4 MB

  qkv_kernel<<<dim3(512), dim3(256), 0, stream>>>(x, wq, bq, wk, bk, wv, bv, qT, kT, vB);
  attn_kernel<<<dim3(512), dim3(256), 0, stream>>>(qT, kT, vB, x, wf, bf_, gamma, out);
}